// Round 6
// baseline (140.848 us; speedup 1.0000x reference)
//
#include <hip/hip_runtime.h>
#include <math.h>

#define NF 1000
#define NC 1000
#define NB 16384
#define NV 250          // NF/4 float4s per row (exact: 1000 = 4*250)
#define ALPHA_C 0.5f
#define BETA_C 0.003f
#define GAMMA_C 0.001f
#define MAXL 512        // LDS row-list capacity (class count ~16.4 +- 4; huge margin)

__device__ __forceinline__ float wave_sum(float v) {
#pragma unroll
    for (int off = 32; off > 0; off >>= 1) v += __shfl_xor(v, off, 64);
    return v;
}
__device__ __forceinline__ float wave_max(float v) {
#pragma unroll
    for (int off = 32; off > 0; off >>= 1) v = fmaxf(v, __shfl_xor(v, off, 64));
    return v;
}

// One block per class. Builds its row list by scanning y (L2-resident),
// then for each row computes CE + ||x-c||^2 via block reductions AND
// accumulates sum_x -- a single read of x for everything. Per-class
// partials written plainly (no contended atomics anywhere).
__global__ __launch_bounds__(256) void class_fused(
    const float* __restrict__ x, const int* __restrict__ y,
    const float* __restrict__ centers,
    float* __restrict__ new_centers, float4* __restrict__ partials) {
    __shared__ int list[MAXL];
    __shared__ int lcount;
    __shared__ float sb[24];
    __shared__ float sxy[2];
    const int c = blockIdx.x, t = threadIdx.x;
    const int wid = t >> 6, lane = t & 63;
    if (t == 0) lcount = 0;
    __syncthreads();

    const int4* y4 = (const int4*)y;
    for (int i = t; i < NB / 4; i += 256) {
        int4 v = y4[i];
        int b = 4 * i;
        if (v.x == c) { int p = atomicAdd(&lcount, 1); list[p & (MAXL - 1)] = b; }
        if (v.y == c) { int p = atomicAdd(&lcount, 1); list[p & (MAXL - 1)] = b + 1; }
        if (v.z == c) { int p = atomicAdd(&lcount, 1); list[p & (MAXL - 1)] = b + 2; }
        if (v.w == c) { int p = atomicAdd(&lcount, 1); list[p & (MAXL - 1)] = b + 3; }
    }
    __syncthreads();
    const int n = lcount;

    float4 cv = make_float4(0.f, 0.f, 0.f, 0.f);
    if (t < NV) cv = ((const float4*)(centers + (size_t)c * NF))[t];
    const int xt = c >> 2, xc = c & 3;   // thread/component holding x[b][c]

    float4 acc = make_float4(0.f, 0.f, 0.f, 0.f);
    float ce_acc = 0.f, s2_acc = 0.f;    // valid on t==0 only

    for (int i = 0; i < n; i += 2) {
        const bool two = (i + 1 < n);
        const int b0 = list[i];
        const int b1 = two ? list[i + 1] : 0;
        float4 v0, v1;
        float m0 = -INFINITY, m1 = -INFINITY;
        if (t < NV) {
            v0 = ((const float4*)(x + (size_t)b0 * NF))[t];
            m0 = fmaxf(fmaxf(v0.x, v0.y), fmaxf(v0.z, v0.w));
            if (two) {
                v1 = ((const float4*)(x + (size_t)b1 * NF))[t];
                m1 = fmaxf(fmaxf(v1.x, v1.y), fmaxf(v1.z, v1.w));
            }
        }
        m0 = wave_max(m0);
        m1 = wave_max(m1);
        __syncthreads();                 // protect sb[0..7] from prev iter reads
        if (lane == 0) { sb[wid] = m0; sb[4 + wid] = m1; }
        if (t == xt) {                   // xt < NV always (c < 1000)
            sxy[0] = (xc == 0) ? v0.x : (xc == 1) ? v0.y : (xc == 2) ? v0.z : v0.w;
            if (two) sxy[1] = (xc == 0) ? v1.x : (xc == 1) ? v1.y : (xc == 2) ? v1.z : v1.w;
        }
        __syncthreads();
        const float rmax0 = fmaxf(fmaxf(sb[0], sb[1]), fmaxf(sb[2], sb[3]));
        const float rmax1 = fmaxf(fmaxf(sb[4], sb[5]), fmaxf(sb[6], sb[7]));

        float e0 = 0.f, e1 = 0.f, d0 = 0.f, d1 = 0.f;
        if (t < NV) {
            e0 = expf(v0.x - rmax0) + expf(v0.y - rmax0) +
                 expf(v0.z - rmax0) + expf(v0.w - rmax0);
            float dx = v0.x - cv.x, dy = v0.y - cv.y;
            float dz = v0.z - cv.z, dw = v0.w - cv.w;
            d0 = dx * dx + dy * dy + dz * dz + dw * dw;
            acc.x += v0.x; acc.y += v0.y; acc.z += v0.z; acc.w += v0.w;
            if (two) {
                e1 = expf(v1.x - rmax1) + expf(v1.y - rmax1) +
                     expf(v1.z - rmax1) + expf(v1.w - rmax1);
                float ex = v1.x - cv.x, ey = v1.y - cv.y;
                float ez = v1.z - cv.z, ew = v1.w - cv.w;
                d1 = ex * ex + ey * ey + ez * ez + ew * ew;
                acc.x += v1.x; acc.y += v1.y; acc.z += v1.z; acc.w += v1.w;
            }
        }
        e0 = wave_sum(e0); e1 = wave_sum(e1);
        d0 = wave_sum(d0); d1 = wave_sum(d1);
        // writes to sb[8..23] are disjoint from the sb[0..7] reads above
        if (lane == 0) { sb[8 + wid] = e0; sb[12 + wid] = e1;
                         sb[16 + wid] = d0; sb[20 + wid] = d1; }
        __syncthreads();
        if (t == 0) {
            float se0 = sb[8] + sb[9] + sb[10] + sb[11];
            float sd0 = sb[16] + sb[17] + sb[18] + sb[19];
            ce_acc += -(sxy[0] - rmax0 - logf(se0));
            s2_acc += sd0;
            if (two) {
                float se1 = sb[12] + sb[13] + sb[14] + sb[15];
                float sd1 = sb[20] + sb[21] + sb[22] + sb[23];
                ce_acc += -(sxy[1] - rmax1 - logf(se1));
                s2_acc += sd1;
            }
        }
    }

    // epilogue: new centers + per-class partials
    const float inv = (n > 0) ? 1.f / (float)n : 0.f;
    float lsq = 0.f, lmd2 = 0.f;
    if (t < NV) {
        float4 md, nc;
        md.x = (n > 0) ? (acc.x * inv - cv.x) : 0.f;
        md.y = (n > 0) ? (acc.y * inv - cv.y) : 0.f;
        md.z = (n > 0) ? (acc.z * inv - cv.z) : 0.f;
        md.w = (n > 0) ? (acc.w * inv - cv.w) : 0.f;
        nc.x = cv.x + ALPHA_C * md.x; nc.y = cv.y + ALPHA_C * md.y;
        nc.z = cv.z + ALPHA_C * md.z; nc.w = cv.w + ALPHA_C * md.w;
        ((float4*)(new_centers + (size_t)c * NF))[t] = nc;
        lsq = nc.x * nc.x + nc.y * nc.y + nc.z * nc.z + nc.w * nc.w;
        lmd2 = md.x * md.x + md.y * md.y + md.z * md.z + md.w * md.w;
    }
    float w0 = wave_sum(lsq), w1 = wave_sum(lmd2);
    __syncthreads();
    if (lane == 0) { sb[wid] = w0; sb[4 + wid] = w1; }
    __syncthreads();
    if (t == 0) {
        float sq = sb[0] + sb[1] + sb[2] + sb[3];
        float md2 = sb[4] + sb[5] + sb[6] + sb[7];
        // per-class intra mean: S2/n - alpha*(2-alpha)*||md||^2
        float intra = (n > 0) ? (s2_acc * inv - ALPHA_C * (2.f - ALPHA_C) * md2) : 0.f;
        partials[c] = make_float4(ce_acc, s2_acc, sq, intra);
    }
}

// Partial column sums, no atomics: block (bx,by) writes s_part[by*NF + f].
__global__ __launch_bounds__(256) void col_partial(
    const float* __restrict__ new_centers, float* __restrict__ s_part) {
    const int f = blockIdx.x * 256 + threadIdx.x;
    if (f >= NF) return;
    float acc = 0.f;
    for (int c = blockIdx.y; c < NC; c += gridDim.y)
        acc += new_centers[(size_t)c * NF + f];
    s_part[blockIdx.y * NF + f] = acc;
}

__global__ __launch_bounds__(1024) void finalize(
    const float* __restrict__ s_part, const float4* __restrict__ partials,
    float* __restrict__ out) {
    __shared__ float sb[80];
    const int t = threadIdx.x;
    float ssq = 0.f, ces = 0.f, s2 = 0.f, sq = 0.f, intra = 0.f;
    if (t < NC) {
        float s = 0.f;
#pragma unroll
        for (int k = 0; k < 16; k++) s += s_part[k * NF + t];
        ssq = s * s;
        float4 p = partials[t];
        ces = p.x; s2 = p.y; sq = p.z; intra = p.w;
    }
    float w0 = wave_sum(ssq), w1 = wave_sum(ces), w2 = wave_sum(s2);
    float w3 = wave_sum(sq), w4 = wave_sum(intra);
    const int wid = t >> 6, lane = t & 63;
    if (lane == 0) {
        sb[wid] = w0; sb[16 + wid] = w1; sb[32 + wid] = w2;
        sb[48 + wid] = w3; sb[64 + wid] = w4;
    }
    __syncthreads();
    if (t == 0) {
        float Sssq = 0.f, Sces = 0.f, Ss2 = 0.f, Ssq = 0.f, Sintra = 0.f;
        for (int k = 0; k < 16; k++) {
            Sssq += sb[k]; Sces += sb[16 + k]; Ss2 += sb[32 + k];
            Ssq += sb[48 + k]; Sintra += sb[64 + k];
        }
        float cem = Sces / (float)NB;
        float cl = Ss2 / (float)NB;
        float num_pairs = (float)NC * (float)(NC - 1) * 0.5f;
        float inter = ((float)NC * Ssq - Sssq) / num_pairs;
        float intra_l = Sintra / (float)NC;
        out[0] = cem + BETA_C * cl + GAMMA_C * inter + GAMMA_C * intra_l;
    }
}

extern "C" void kernel_launch(void* const* d_in, const int* in_sizes, int n_in,
                              void* d_out, int out_size, void* d_ws, size_t ws_size,
                              hipStream_t stream) {
    const float* x = (const float*)d_in[0];
    const int* y = (const int*)d_in[1];
    const float* centers = (const float*)d_in[2];
    float* out = (float*)d_out;

    char* ws = (char*)d_ws;
    float* s_part      = (float*)(ws);                 // 16*1000*4 = 64,000 B
    float4* partials   = (float4*)(ws + 64000);        // 16,000 B
    float* new_centers = (float*)(ws + 80000);         // 4,000,000 B
    // everything read is written this launch -- no memset needed

    class_fused<<<NC, 256, 0, stream>>>(x, y, centers, new_centers, partials);
    dim3 cgrid(4, 16);
    col_partial<<<cgrid, 256, 0, stream>>>(new_centers, s_part);
    finalize<<<1, 1024, 0, stream>>>(s_part, partials, out);
}